// Round 2
// baseline (653.529 us; speedup 1.0000x reference)
//
#include <hip/hip_runtime.h>
#include <hip/hip_bf16.h>

// Swapped-operand bf16-MFMA attention with materialized attn.
// B=64, TQ=TK=1024, DK=DV=64. WG = 256 thr = 4 waves; 16 queries/WG;
// wave w owns keys [w*256, w*256+256).
//
// S^T = mfma(K, Q): MFMA C-layout puts (col = query = lane&15,
// key = quad*4+reg). Consecutive keys in consecutive regs of one lane:
//   - int4 mask loads    (16 instead of 64 scalar per lane)
//   - float4 attn stores (16 instead of 64 scalar per lane)
//   - lane-local softmax key-reduction (+2 shuffles instead of 16)
//   - float4 out stores
// PV uses the round-0 VERIFIED V^T staging (scalar V loads pair-packed to
// [d][k] bf16 LDS rows, VSTR=40) and ds_read_b128 fragment reads — no asm.
// New vs round 0: V loads are software-pipelined one chunk ahead (chunk 0
// issued before softmax, chunk c+1 issued under chunk c's stage/MFMA), and
// P is packed to LDS in two 128-key halves so total LDS = 38400 B -> 4 WG/CU.

#define B_   64
#define TQ_  1024
#define TK_  1024
#define DD   64

typedef short short8 __attribute__((ext_vector_type(8)));
typedef float f32x4 __attribute__((ext_vector_type(4)));

#define PLW    68                  // u32 per P row: 64 data + 4 pad
#define PL_U32 (16 * PLW)          // 1088 u32 = 4352 B (P half / O stage)
#define VSTR   40                  // shorts per V^T row: 32 keys + 8 pad (80 B, 16B-aligned)
#define VT_SH  (64 * VSTR)         // 2560 shorts = 5120 B
#define WVS    (2 * PL_U32 + VT_SH) // 4736 shorts = 9472 B per wave
// LDS: 4*9472 + 512 (red) = 38400 B -> 4 WG/CU (16 waves)

__device__ __forceinline__ unsigned cvt2(float a, float b) {
    __hip_bfloat162 h = __float22bfloat162_rn(make_float2(a, b));
    unsigned u; __builtin_memcpy(&u, &h, 4); return u;
}

union Frag { short8 s; unsigned u[4]; };

__global__ __launch_bounds__(256, 4) void attn_mfma_kernel(
    const float* __restrict__ qg, const float* __restrict__ kg,
    const float* __restrict__ vg, const int* __restrict__ maskg,
    float* __restrict__ outg, float* __restrict__ attng)
{
    __shared__ __align__(16) short lds[4 * WVS];   // 37888 B
    __shared__ float red[128];                     // [0:64) max, [64:128) sum

    const int t    = threadIdx.x;
    const int wave = t >> 6, lane = t & 63;
    const int quad = lane >> 4, n16 = lane & 15;
    const int b    = blockIdx.y;
    const int q0   = blockIdx.x * 16;
    const int kbase = wave * 256;

    short*    wbase = lds + wave * WVS;
    unsigned* pl    = (unsigned*)wbase;       // [16 q][68 u32] (bf16 pairs / f32 O-stage)
    short*    vw    = wbase + 2 * PL_U32;     // [64 d][VSTR]  V^T chunk (32 keys)

    // ---- Q frags (B operand), pre-scaled by 1/sqrt(64)=0.125 (exact pow2) ----
    Frag aq[2];
    {
        const float* qp = qg + ((size_t)(b * TQ_ + q0 + n16)) * DD + quad * 8;
        #pragma unroll
        for (int f = 0; f < 2; ++f) {
            float4 x = *(const float4*)(qp + f * 32);
            float4 y = *(const float4*)(qp + f * 32 + 4);
            aq[f].u[0] = cvt2(0.125f * x.x, 0.125f * x.y);
            aq[f].u[1] = cvt2(0.125f * x.z, 0.125f * x.w);
            aq[f].u[2] = cvt2(0.125f * y.x, 0.125f * y.y);
            aq[f].u[3] = cvt2(0.125f * y.z, 0.125f * y.w);
        }
    }

    float s_reg[64];  // s_reg[kt*4+r]: key kbase+kt*16+quad*4+r, query q0+n16

    // ================= S^T = (K)(Q^T*0.125) + mask =================
    const float* kbp  = kg + (size_t)b * TK_ * DD;
    const int*   mrow = maskg + ((size_t)(b * TQ_ + q0 + n16)) * TK_ + kbase + quad * 4;
    #pragma unroll
    for (int kt = 0; kt < 16; ++kt) {
        const float* kp = kbp + (size_t)(kbase + kt * 16 + n16) * DD + quad * 8;
        Frag bk[2];
        #pragma unroll
        for (int f = 0; f < 2; ++f) {
            float4 x = *(const float4*)(kp + f * 32);
            float4 y = *(const float4*)(kp + f * 32 + 4);
            bk[f].u[0] = cvt2(x.x, x.y); bk[f].u[1] = cvt2(x.z, x.w);
            bk[f].u[2] = cvt2(y.x, y.y); bk[f].u[3] = cvt2(y.z, y.w);
        }
        const int4 mk = *(const int4*)(mrow + kt * 16);
        f32x4 acc = {0.f, 0.f, 0.f, 0.f};
        acc = __builtin_amdgcn_mfma_f32_16x16x32_bf16(bk[0].s, aq[0].s, acc, 0, 0, 0);
        acc = __builtin_amdgcn_mfma_f32_16x16x32_bf16(bk[1].s, aq[1].s, acc, 0, 0, 0);
        s_reg[kt * 4 + 0] = acc[0] + (mk.x ? 0.f : -1e9f);
        s_reg[kt * 4 + 1] = acc[1] + (mk.y ? 0.f : -1e9f);
        s_reg[kt * 4 + 2] = acc[2] + (mk.z ? 0.f : -1e9f);
        s_reg[kt * 4 + 3] = acc[3] + (mk.w ? 0.f : -1e9f);
    }

    // ---- issue V chunk-0 loads now; latency hides under softmax ----
    const float* vbp = vg + (size_t)b * TK_ * DD;
    unsigned va16[16];   // packed bf16 pairs: V[ck+2i..2i+1][d=lane]
    #pragma unroll
    for (int i = 0; i < 16; ++i) {
        const float v0 = vbp[(size_t)(kbase + 2 * i) * DD + lane];
        const float v1 = vbp[(size_t)(kbase + 2 * i + 1) * DD + lane];
        va16[i] = cvt2(v0, v1);
    }

    // ================= softmax (lane-local keys + 2 shuffles + LDS x-wave) ====
    float m8[8];
    #pragma unroll
    for (int j = 0; j < 8; ++j) m8[j] = s_reg[j];
    #pragma unroll
    for (int i = 8; i < 64; i += 8)
        #pragma unroll
        for (int j = 0; j < 8; ++j) m8[j] = fmaxf(m8[j], s_reg[i + j]);
    float m = fmaxf(fmaxf(fmaxf(m8[0], m8[1]), fmaxf(m8[2], m8[3])),
                    fmaxf(fmaxf(m8[4], m8[5]), fmaxf(m8[6], m8[7])));
    m = fmaxf(m, __shfl_xor(m, 16));
    m = fmaxf(m, __shfl_xor(m, 32));
    if (lane < 16) red[wave * 16 + n16] = m;
    __syncthreads();
    const float gm = fmaxf(fmaxf(red[n16], red[16 + n16]),
                           fmaxf(red[32 + n16], red[48 + n16]));
    float l0 = 0.f, l1 = 0.f, l2 = 0.f, l3 = 0.f;
    #pragma unroll
    for (int i = 0; i < 16; ++i) {
        const float p0 = __expf(s_reg[4*i+0] - gm);
        const float p1 = __expf(s_reg[4*i+1] - gm);
        const float p2 = __expf(s_reg[4*i+2] - gm);
        const float p3 = __expf(s_reg[4*i+3] - gm);
        s_reg[4*i+0] = p0; s_reg[4*i+1] = p1;
        s_reg[4*i+2] = p2; s_reg[4*i+3] = p3;
        l0 += p0; l1 += p1; l2 += p2; l3 += p3;
    }
    float lsum = (l0 + l1) + (l2 + l3);
    lsum += __shfl_xor(lsum, 16);
    lsum += __shfl_xor(lsum, 32);
    if (lane < 16) red[64 + wave * 16 + n16] = lsum;
    __syncthreads();
    const float inv = 1.f / (red[64 + n16] + red[80 + n16] +
                             red[96 + n16] + red[112 + n16]);
    #pragma unroll
    for (int i = 0; i < 64; ++i) s_reg[i] *= inv;

    // ---- attn: 16 x float4 stores; pack low 128 keys (bf16) into P-LDS ----
    float* ab = attng + ((size_t)(b * TQ_ + q0 + n16)) * TK_ + kbase + quad * 4;
    #pragma unroll
    for (int kt = 0; kt < 16; ++kt)
        *(float4*)(ab + kt * 16) = make_float4(s_reg[kt*4+0], s_reg[kt*4+1],
                                               s_reg[kt*4+2], s_reg[kt*4+3]);
    #pragma unroll
    for (int kt = 0; kt < 8; ++kt) {
        uint2 u;
        u.x = cvt2(s_reg[kt*4+0], s_reg[kt*4+1]);
        u.y = cvt2(s_reg[kt*4+2], s_reg[kt*4+3]);
        *(uint2*)&pl[n16 * PLW + kt * 8 + quad * 2] = u;
    }

    // ================= O^T = (V^T)(P^T), 32-key chunks ======================
    f32x4 oacc[4];
    #pragma unroll
    for (int dg = 0; dg < 4; ++dg) oacc[dg] = (f32x4){0.f, 0.f, 0.f, 0.f};

    #pragma unroll 1
    for (int c = 0; c < 4; ++c) {
        // stage chunk c: V^T[d = lane][key pairs] (wave-private; same-wave DS
        // ops are in-order, so prior-iteration b128 reads see old data)
        #pragma unroll
        for (int i = 0; i < 16; ++i)
            *(unsigned*)(vw + lane * VSTR + 2 * i) = va16[i];
        // prefetch chunk c+1 (independent; overlaps stage + MFMAs)
        {
            const int ck = kbase + (c + 1) * 32;
            #pragma unroll
            for (int i = 0; i < 16; ++i) {
                const float v0 = vbp[(size_t)(ck + 2 * i) * DD + lane];
                const float v1 = vbp[(size_t)(ck + 2 * i + 1) * DD + lane];
                va16[i] = cvt2(v0, v1);
            }
        }
        Frag pf;
        pf.s = *(const short8*)&pl[n16 * PLW + c * 16 + quad * 4];
        #pragma unroll
        for (int dg = 0; dg < 4; ++dg) {
            Frag vf;
            vf.s = *(const short8*)(vw + (dg * 16 + n16) * VSTR + quad * 8);
            oacc[dg] = __builtin_amdgcn_mfma_f32_16x16x32_bf16(vf.s, pf.s, oacc[dg], 0, 0, 0);
        }
    }

    // pack high 128 keys into P-LDS (after loop-1 pf reads; same-wave DS in-order)
    #pragma unroll
    for (int kt = 8; kt < 16; ++kt) {
        uint2 u;
        u.x = cvt2(s_reg[kt*4+0], s_reg[kt*4+1]);
        u.y = cvt2(s_reg[kt*4+2], s_reg[kt*4+3]);
        *(uint2*)&pl[n16 * PLW + (kt - 8) * 8 + quad * 2] = u;
    }

    #pragma unroll 1
    for (int c = 0; c < 4; ++c) {   // global chunks 4..7
        #pragma unroll
        for (int i = 0; i < 16; ++i)
            *(unsigned*)(vw + lane * VSTR + 2 * i) = va16[i];
        if (c < 3) {
            const int ck = kbase + (c + 5) * 32;
            #pragma unroll
            for (int i = 0; i < 16; ++i) {
                const float v0 = vbp[(size_t)(ck + 2 * i) * DD + lane];
                const float v1 = vbp[(size_t)(ck + 2 * i + 1) * DD + lane];
                va16[i] = cvt2(v0, v1);
            }
        }
        Frag pf;
        pf.s = *(const short8*)&pl[n16 * PLW + c * 16 + quad * 4];
        #pragma unroll
        for (int dg = 0; dg < 4; ++dg) {
            Frag vf;
            vf.s = *(const short8*)(vw + (dg * 16 + n16) * VSTR + quad * 8);
            oacc[dg] = __builtin_amdgcn_mfma_f32_16x16x32_bf16(vf.s, pf.s, oacc[dg], 0, 0, 0);
        }
    }

    // ---- cross-wave O reduction: stage O^T (f32) into own P region ----
    // oacc[dg][r]: d = dg*16 + quad*4 + r, q = n16
    float* ow = (float*)pl;
    #pragma unroll
    for (int dg = 0; dg < 4; ++dg)
        *(f32x4*)&ow[n16 * PLW + dg * 16 + quad * 4] = oacc[dg];
    __syncthreads();
    {
        const int row = t >> 4, col = (t & 15) * 4;
        const float* base = (const float*)lds;
        float4 o = make_float4(0.f, 0.f, 0.f, 0.f);
        #pragma unroll
        for (int w = 0; w < 4; ++w) {
            const float4 x = *(const float4*)(base + w * (WVS / 2) + row * PLW + col);
            o.x += x.x; o.y += x.y; o.z += x.z; o.w += x.w;
        }
        *(float4*)(outg + ((size_t)(b * TQ_ + q0 + row)) * DD + col) = o;
    }
}

extern "C" void kernel_launch(void* const* d_in, const int* in_sizes, int n_in,
                              void* d_out, int out_size, void* d_ws, size_t ws_size,
                              hipStream_t stream) {
    const float* q    = (const float*)d_in[0];
    const float* k    = (const float*)d_in[1];
    const float* v    = (const float*)d_in[2];
    const int*   mask = (const int*)d_in[3];

    float* out  = (float*)d_out;                   // [64][1024][64]
    float* attn = out + (size_t)B_ * TQ_ * DD;     // [64][1024][1024]

    dim3 grid(TQ_ / 16, B_);
    attn_mfma_kernel<<<grid, 256, 0, stream>>>(q, k, v, mask, out, attn);
}

// Round 3
// 645.959 us; speedup vs baseline: 1.0117x; 1.0117x over previous
//
#include <hip/hip_runtime.h>
#include <hip/hip_bf16.h>

// Swapped-operand bf16-MFMA attention with materialized attn.
// B=64, TQ=TK=1024, DK=DV=64. WG = 256 thr = 4 waves; 16 queries/WG;
// wave w owns keys [w*256, w*256+256).
//
// v3 changes (latency-bound fix; R2 showed 2 TB/s with everything idle):
//  - V is loaded DIRECTLY from global into MFMA A-fragments (scalar gather
//    V[k][d], d=dg*16+n16, k=quad*8+j), packed to bf16 in-register. No V LDS
//    staging at all: -128 ds_write, -32 ds_read per lane, no stage->read
//    serialization. 1-chunk-ahead raw-f32 prefetch pipeline; chunk 0 issued
//    before softmax.
//  - mask int4 loads hoisted 8-deep ahead of the QK^T MFMAs.
//  - launch_bounds(256,3): trade occupancy for register headroom (R2's
//    64-VGPR allocation strangled memory-level parallelism).
//  - batch-clustered XCD swizzle: each XCD owns 8 batches -> K/V/Q stay
//    L2-resident (~1.5 MB working set vs 4 MB L2 per XCD).
// P packed fully to LDS (round-0-verified PSTR=264 layout) before PV so
// s_reg is dead during PV. LDS = 4*8448 + 512 = 34304 B.

#define B_   64
#define TQ_  1024
#define TK_  1024
#define DD   64

typedef short short8 __attribute__((ext_vector_type(8)));
typedef float f32x4 __attribute__((ext_vector_type(4)));

#define PSTR 264               // shorts per P row (256 keys + 8 pad, 16B-aligned)
#define WVS  (16 * PSTR)       // 4224 shorts = 8448 B per wave (P / O-stage)

__device__ __forceinline__ unsigned cvt2(float a, float b) {
    __hip_bfloat162 h = __float22bfloat162_rn(make_float2(a, b));
    unsigned u; __builtin_memcpy(&u, &h, 4); return u;
}

union Frag { short8 s; unsigned u[4]; };

__global__ __launch_bounds__(256, 3) void attn_mfma_kernel(
    const float* __restrict__ qg, const float* __restrict__ kg,
    const float* __restrict__ vg, const int* __restrict__ maskg,
    float* __restrict__ outg, float* __restrict__ attng)
{
    __shared__ __align__(16) short lds[4 * WVS];   // 33792 B
    __shared__ float red[128];                     // [0:64) max, [64:128) sum

    const int t    = threadIdx.x;
    const int wave = t >> 6, lane = t & 63;
    const int quad = lane >> 4, n16 = lane & 15;

    // batch-clustered XCD swizzle: flat id -> (xcd, slot); each XCD owns
    // batches [xcd*8, xcd*8+8). Bijective over the 4096-block grid.
    const int flat = blockIdx.y * 64 + blockIdx.x;
    const int xcd  = flat & 7, slot = flat >> 3;
    const int b    = (xcd << 3) | (slot & 7);
    const int q0   = (slot >> 3) << 4;
    const int kbase = wave * 256;

    short* pw = lds + wave * WVS;

    // ---- Q frags (B operand), pre-scaled by 1/sqrt(64)=0.125 (exact pow2) ----
    Frag aq[2];
    {
        const float* qp = qg + ((size_t)(b * TQ_ + q0 + n16)) * DD + quad * 8;
        #pragma unroll
        for (int f = 0; f < 2; ++f) {
            float4 x = *(const float4*)(qp + f * 32);
            float4 y = *(const float4*)(qp + f * 32 + 4);
            aq[f].u[0] = cvt2(0.125f * x.x, 0.125f * x.y);
            aq[f].u[1] = cvt2(0.125f * x.z, 0.125f * x.w);
            aq[f].u[2] = cvt2(0.125f * y.x, 0.125f * y.y);
            aq[f].u[3] = cvt2(0.125f * y.z, 0.125f * y.w);
        }
    }

    float s_reg[64];  // s_reg[kt*4+r]: key kbase+kt*16+quad*4+r, query q0+n16

    // ================= S^T = (K)(Q^T*0.125) + mask =================
    const float* kbp  = kg + (size_t)b * TK_ * DD;
    const int*   mrow = maskg + ((size_t)(b * TQ_ + q0 + n16)) * TK_ + kbase + quad * 4;
    #pragma unroll
    for (int h = 0; h < 2; ++h) {
        int4 mk[8];
        #pragma unroll
        for (int i = 0; i < 8; ++i)            // 8 mask loads in flight
            mk[i] = *(const int4*)(mrow + (h * 8 + i) * 16);
        #pragma unroll
        for (int i = 0; i < 8; ++i) {
            const int kt = h * 8 + i;
            const float* kp = kbp + (size_t)(kbase + kt * 16 + n16) * DD + quad * 8;
            Frag bk[2];
            #pragma unroll
            for (int f = 0; f < 2; ++f) {
                float4 x = *(const float4*)(kp + f * 32);
                float4 y = *(const float4*)(kp + f * 32 + 4);
                bk[f].u[0] = cvt2(x.x, x.y); bk[f].u[1] = cvt2(x.z, x.w);
                bk[f].u[2] = cvt2(y.x, y.y); bk[f].u[3] = cvt2(y.z, y.w);
            }
            f32x4 acc = {0.f, 0.f, 0.f, 0.f};
            acc = __builtin_amdgcn_mfma_f32_16x16x32_bf16(bk[0].s, aq[0].s, acc, 0, 0, 0);
            acc = __builtin_amdgcn_mfma_f32_16x16x32_bf16(bk[1].s, aq[1].s, acc, 0, 0, 0);
            s_reg[kt * 4 + 0] = acc[0] + (mk[i].x ? 0.f : -1e9f);
            s_reg[kt * 4 + 1] = acc[1] + (mk[i].y ? 0.f : -1e9f);
            s_reg[kt * 4 + 2] = acc[2] + (mk[i].z ? 0.f : -1e9f);
            s_reg[kt * 4 + 3] = acc[3] + (mk[i].w ? 0.f : -1e9f);
        }
    }

    // ---- issue V chunk-0 raw loads now; latency hides under softmax ----
    // vraw[dg*8+j] = V[kbase + c*32 + quad*8 + j][dg*16 + n16]
    const float* vb0 = vg + (size_t)b * TK_ * DD
                     + (size_t)(kbase + quad * 8) * DD + n16;
    float vraw[32];
    #pragma unroll
    for (int u = 0; u < 32; ++u)
        vraw[u] = vb0[(size_t)(u & 7) * DD + (u >> 3) * 16];

    // ================= softmax (lane-local keys + 2 shuffles + LDS x-wave) ====
    float m8[8];
    #pragma unroll
    for (int j = 0; j < 8; ++j) m8[j] = s_reg[j];
    #pragma unroll
    for (int i = 8; i < 64; i += 8)
        #pragma unroll
        for (int j = 0; j < 8; ++j) m8[j] = fmaxf(m8[j], s_reg[i + j]);
    float m = fmaxf(fmaxf(fmaxf(m8[0], m8[1]), fmaxf(m8[2], m8[3])),
                    fmaxf(fmaxf(m8[4], m8[5]), fmaxf(m8[6], m8[7])));
    m = fmaxf(m, __shfl_xor(m, 16));
    m = fmaxf(m, __shfl_xor(m, 32));
    if (lane < 16) red[wave * 16 + n16] = m;
    __syncthreads();
    const float gm = fmaxf(fmaxf(red[n16], red[16 + n16]),
                           fmaxf(red[32 + n16], red[48 + n16]));
    float l0 = 0.f, l1 = 0.f, l2 = 0.f, l3 = 0.f;
    #pragma unroll
    for (int i = 0; i < 16; ++i) {
        const float p0 = __expf(s_reg[4*i+0] - gm);
        const float p1 = __expf(s_reg[4*i+1] - gm);
        const float p2 = __expf(s_reg[4*i+2] - gm);
        const float p3 = __expf(s_reg[4*i+3] - gm);
        s_reg[4*i+0] = p0; s_reg[4*i+1] = p1;
        s_reg[4*i+2] = p2; s_reg[4*i+3] = p3;
        l0 += p0; l1 += p1; l2 += p2; l3 += p3;
    }
    float lsum = (l0 + l1) + (l2 + l3);
    lsum += __shfl_xor(lsum, 16);
    lsum += __shfl_xor(lsum, 32);
    if (lane < 16) red[64 + wave * 16 + n16] = lsum;
    __syncthreads();
    const float inv = 1.f / (red[64 + n16] + red[80 + n16] +
                             red[96 + n16] + red[112 + n16]);
    #pragma unroll
    for (int i = 0; i < 64; ++i) s_reg[i] *= inv;

    // ---- attn: 16 x float4 stores; pack ALL of P (bf16) into LDS ----
    float* ab = attng + ((size_t)(b * TQ_ + q0 + n16)) * TK_ + kbase + quad * 4;
    #pragma unroll
    for (int kt = 0; kt < 16; ++kt)
        *(float4*)(ab + kt * 16) = make_float4(s_reg[kt*4+0], s_reg[kt*4+1],
                                               s_reg[kt*4+2], s_reg[kt*4+3]);
    #pragma unroll
    for (int kt = 0; kt < 16; ++kt) {
        uint2 u;
        u.x = cvt2(s_reg[kt*4+0], s_reg[kt*4+1]);
        u.y = cvt2(s_reg[kt*4+2], s_reg[kt*4+3]);
        *(uint2*)(pw + n16 * PSTR + kt * 16 + quad * 4) = u;
    }
    // s_reg dead from here: registers free for the PV pipeline.

    // ================= O^T = (V^T)(P^T), 32-key chunks, V from registers =====
    f32x4 oacc[4];
    #pragma unroll
    for (int dg = 0; dg < 4; ++dg) oacc[dg] = (f32x4){0.f, 0.f, 0.f, 0.f};

    #pragma unroll
    for (int c = 0; c < 8; ++c) {
        // pack chunk c raw -> bf16 A-frags (waits on chunk-c loads)
        unsigned va16[16];
        #pragma unroll
        for (int dg = 0; dg < 4; ++dg)
            #pragma unroll
            for (int w = 0; w < 4; ++w)
                va16[dg * 4 + w] = cvt2(vraw[dg * 8 + 2 * w], vraw[dg * 8 + 2 * w + 1]);
        // issue chunk c+1 raw loads (overlap P read + MFMAs + next pack)
        if (c < 7) {
            #pragma unroll
            for (int u = 0; u < 32; ++u)
                vraw[u] = vb0[(size_t)((c + 1) * 32 + (u & 7)) * DD + (u >> 3) * 16];
        }
        Frag pf;
        pf.s = *(const short8*)(pw + n16 * PSTR + c * 32 + quad * 8);
        #pragma unroll
        for (int dg = 0; dg < 4; ++dg) {
            Frag af;
            af.u[0] = va16[dg*4+0]; af.u[1] = va16[dg*4+1];
            af.u[2] = va16[dg*4+2]; af.u[3] = va16[dg*4+3];
            oacc[dg] = __builtin_amdgcn_mfma_f32_16x16x32_bf16(af.s, pf.s, oacc[dg], 0, 0, 0);
        }
    }

    // ---- cross-wave O reduction: stage O^T (f32) into own P region ----
    // oacc[dg][r]: d = dg*16 + quad*4 + r, q = n16
    float* ow = (float*)pw;
    #pragma unroll
    for (int dg = 0; dg < 4; ++dg)
        *(f32x4*)&ow[n16 * 68 + dg * 16 + quad * 4] = oacc[dg];
    __syncthreads();
    {
        const int row = t >> 4, col = (t & 15) * 4;
        const float* base = (const float*)lds;
        float4 o = make_float4(0.f, 0.f, 0.f, 0.f);
        #pragma unroll
        for (int w = 0; w < 4; ++w) {
            const float4 x = *(const float4*)(base + w * (WVS / 2) + row * 68 + col);
            o.x += x.x; o.y += x.y; o.z += x.z; o.w += x.w;
        }
        *(float4*)(outg + ((size_t)(b * TQ_ + q0 + row)) * DD + col) = o;
    }
}

extern "C" void kernel_launch(void* const* d_in, const int* in_sizes, int n_in,
                              void* d_out, int out_size, void* d_ws, size_t ws_size,
                              hipStream_t stream) {
    const float* q    = (const float*)d_in[0];
    const float* k    = (const float*)d_in[1];
    const float* v    = (const float*)d_in[2];
    const int*   mask = (const int*)d_in[3];

    float* out  = (float*)d_out;                   // [64][1024][64]
    float* attn = out + (size_t)B_ * TQ_ * DD;     // [64][1024][1024]

    dim3 grid(TQ_ / 16, B_);
    attn_mfma_kernel<<<grid, 256, 0, stream>>>(q, k, v, mask, out, attn);
}

// Round 4
// 634.575 us; speedup vs baseline: 1.0299x; 1.0179x over previous
//
#include <hip/hip_runtime.h>
#include <hip/hip_bf16.h>

// Two-pass bf16-MFMA attention with materialized attn.
// B=64, TQ=TK=1024, DK=DV=64.
//
// Pass 1 (prep): pure streaming, max MLP —
//   - mask int32 -> 1 bit/entry  (268 MB -> 8.4 MB read in main pass)
//   - Q -> bf16, 1/sqrt(64)=0.125 folded in
//   - K -> bf16
//   - V -> V^T bf16 [b][d][k]  (k contiguous: PV A-frags become short8 loads)
// Pass 2 (main): WG=256=4 waves, 16 queries/WG, wave w owns keys [w*256,+256).
//   S^T = mfma(K,Q) (R2/R3-verified layout); all K frags short8, issued
//   up-front (512 B/lane in flight); mask via bit-extract from 2 uint4;
//   V^T A-frags loaded directly (no LDS staging, 1-chunk prefetch);
//   P through LDS (R0-verified PSTR=264); O cross-wave reduce as before.
// Falls back to the R3 single-pass kernel if ws_size < 32 MiB.

#define B_   64
#define TQ_  1024
#define TK_  1024
#define DD   64

typedef short short8 __attribute__((ext_vector_type(8)));
typedef float f32x4 __attribute__((ext_vector_type(4)));

#define PSTR 264               // shorts per P row (256 keys + 8 pad)
#define WVS  (16 * PSTR)       // 4224 shorts = 8448 B per wave

// workspace layout
#define QB_OFF  (0u)
#define KB_OFF  (8u << 20)
#define VT_OFF  (16u << 20)
#define MB_OFF  (24u << 20)
#define WS_NEED (32u << 20)    // 33554432 B

__device__ __forceinline__ unsigned cvt2(float a, float b) {
    __hip_bfloat162 h = __float22bfloat162_rn(make_float2(a, b));
    unsigned u; __builtin_memcpy(&u, &h, 4); return u;
}
__device__ __forceinline__ short cvt1(float a) {
    __hip_bfloat16 h = __float2bfloat16(a);
    short s; __builtin_memcpy(&s, &h, 2); return s;
}

union Frag { short8 s; unsigned u[4]; };

// ============================ PREP PASS ============================
// grid: [0,8192) mask-pack | [8192,10240) Q | [10240,12288) K | [12288,12352) V^T
__global__ __launch_bounds__(256) void prep_kernel(
    const float* __restrict__ qg, const float* __restrict__ kg,
    const float* __restrict__ vg, const int* __restrict__ maskg,
    unsigned char* __restrict__ ws)
{
    const int t = threadIdx.x;
    const int gid = blockIdx.x;
    if (gid < 8192) {
        // one u32 of mask bits per thread: bit i = mask[widx*32 + i] & 1
        const int widx = gid * 256 + t;
        const int4* mp = (const int4*)(maskg + (size_t)widx * 32);
        unsigned bits = 0;
        #pragma unroll
        for (int i = 0; i < 8; ++i) {
            const int4 x = mp[i];
            bits |= (unsigned)(x.x & 1) << (4 * i)
                 |  (unsigned)(x.y & 1) << (4 * i + 1)
                 |  (unsigned)(x.z & 1) << (4 * i + 2)
                 |  (unsigned)(x.w & 1) << (4 * i + 3);
        }
        ((unsigned*)(ws + MB_OFF))[widx] = bits;
    } else if (gid < 8192 + 2048) {
        const int i8 = (gid - 8192) * 256 + t;      // 8 floats per thread
        const float* p = qg + (size_t)i8 * 8;
        const float4 x = *(const float4*)p, y = *(const float4*)(p + 4);
        uint4 o;
        o.x = cvt2(0.125f * x.x, 0.125f * x.y); o.y = cvt2(0.125f * x.z, 0.125f * x.w);
        o.z = cvt2(0.125f * y.x, 0.125f * y.y); o.w = cvt2(0.125f * y.z, 0.125f * y.w);
        ((uint4*)(ws + QB_OFF))[i8] = o;
    } else if (gid < 8192 + 4096) {
        const int i8 = (gid - 8192 - 2048) * 256 + t;
        const float* p = kg + (size_t)i8 * 8;
        const float4 x = *(const float4*)p, y = *(const float4*)(p + 4);
        uint4 o;
        o.x = cvt2(x.x, x.y); o.y = cvt2(x.z, x.w);
        o.z = cvt2(y.x, y.y); o.w = cvt2(y.z, y.w);
        ((uint4*)(ws + KB_OFF))[i8] = o;
    } else {
        // V^T for one batch: [1024 k][64 d] f32 -> [64 d][1024 k] bf16
        __shared__ short tl[64][72];   // row 144 B (16-aligned), k contiguous
        const int b = gid - (8192 + 4096);
        const float* vb = vg + (size_t)b * TK_ * DD;
        short* ob = (short*)(ws + VT_OFF) + (size_t)b * DD * TK_;
        for (int tile = 0; tile < 16; ++tile) {
            const int k0 = tile * 64;
            #pragma unroll
            for (int i = 0; i < 4; ++i) {
                const int row = i * 16 + (t >> 4);
                const int d   = (t & 15) * 4;
                const float4 x = *(const float4*)(vb + (size_t)(k0 + row) * DD + d);
                tl[d + 0][row] = cvt1(x.x); tl[d + 1][row] = cvt1(x.y);
                tl[d + 2][row] = cvt1(x.z); tl[d + 3][row] = cvt1(x.w);
            }
            __syncthreads();
            #pragma unroll
            for (int p = 0; p < 2; ++p) {
                const int d = p * 32 + (t >> 3);
                const uint4 val = *(const uint4*)&tl[d][(t & 7) * 8];
                *(uint4*)(ob + (size_t)d * TK_ + k0 + (t & 7) * 8) = val;
            }
            __syncthreads();
        }
    }
}

// ============================ MAIN PASS ============================
__global__ __launch_bounds__(256, 4) void attn_bf16_kernel(
    const unsigned char* __restrict__ ws,
    float* __restrict__ outg, float* __restrict__ attng)
{
    __shared__ __align__(16) short lds[4 * WVS];   // 33792 B
    __shared__ float red[128];

    const int t    = threadIdx.x;
    const int wave = t >> 6, lane = t & 63;
    const int quad = lane >> 4, n16 = lane & 15;
    const int b    = blockIdx.y;            // natural order (R0: best FETCH)
    const int q0   = blockIdx.x * 16;
    const int kbase = wave * 256;

    const short*    Qb = (const short*)(ws + QB_OFF);
    const short*    Kb = (const short*)(ws + KB_OFF);
    const short*    Vt = (const short*)(ws + VT_OFF);
    const unsigned* Mb = (const unsigned*)(ws + MB_OFF);

    short* pw = lds + wave * WVS;

    // ---- mask words first (uncached stream, longest latency) ----
    const unsigned* mrow = Mb + ((size_t)(b * TQ_ + q0 + n16)) * 32 + wave * 8;
    const uint4 mw0 = *(const uint4*)(mrow);
    const uint4 mw1 = *(const uint4*)(mrow + 4);

    // ---- Q frags (bf16, pre-scaled) ----
    const short* qp = Qb + ((size_t)(b * TQ_ + q0 + n16)) * DD + quad * 8;
    Frag qf0, qf1;
    qf0.s = *(const short8*)(qp);
    qf1.s = *(const short8*)(qp + 32);

    // ---- V chunk-0 A-frags (direct from V^T, k contiguous) ----
    const short* vrow = Vt + (size_t)b * DD * TK_ + (size_t)n16 * TK_ + kbase + quad * 8;
    Frag vf[4];
    #pragma unroll
    for (int dg = 0; dg < 4; ++dg)
        vf[dg].s = *(const short8*)(vrow + (size_t)(dg * 16) * TK_);

    // ---- all 16 K-row frag pairs issued up-front (512 B/lane in flight) ----
    const short* kbp = Kb + (size_t)(b * TK_ + kbase) * DD;
    Frag kf[16][2];
    #pragma unroll
    for (int kt = 0; kt < 16; ++kt) {
        const short* kp = kbp + (size_t)(kt * 16 + n16) * DD + quad * 8;
        kf[kt][0].s = *(const short8*)(kp);
        kf[kt][1].s = *(const short8*)(kp + 32);
    }

    // ================= S^T = (K)(Q*0.125) + mask-bits =================
    float s_reg[64];  // s_reg[kt*4+r]: key kbase+kt*16+quad*4+r, query q0+n16
    const unsigned mwa[8] = {mw0.x, mw0.y, mw0.z, mw0.w, mw1.x, mw1.y, mw1.z, mw1.w};
    #pragma unroll
    for (int kt = 0; kt < 16; ++kt) {
        f32x4 acc = {0.f, 0.f, 0.f, 0.f};
        acc = __builtin_amdgcn_mfma_f32_16x16x32_bf16(kf[kt][0].s, qf0.s, acc, 0, 0, 0);
        acc = __builtin_amdgcn_mfma_f32_16x16x32_bf16(kf[kt][1].s, qf1.s, acc, 0, 0, 0);
        const unsigned m4 = (mwa[kt >> 1] >> (((kt & 1) << 4) | (quad << 2))) & 15u;
        s_reg[kt * 4 + 0] = acc[0] + ((m4 & 1u) ? 0.f : -1e9f);
        s_reg[kt * 4 + 1] = acc[1] + ((m4 & 2u) ? 0.f : -1e9f);
        s_reg[kt * 4 + 2] = acc[2] + ((m4 & 4u) ? 0.f : -1e9f);
        s_reg[kt * 4 + 3] = acc[3] + ((m4 & 8u) ? 0.f : -1e9f);
    }

    // ================= softmax =================
    float m8[8];
    #pragma unroll
    for (int j = 0; j < 8; ++j) m8[j] = s_reg[j];
    #pragma unroll
    for (int i = 8; i < 64; i += 8)
        #pragma unroll
        for (int j = 0; j < 8; ++j) m8[j] = fmaxf(m8[j], s_reg[i + j]);
    float m = fmaxf(fmaxf(fmaxf(m8[0], m8[1]), fmaxf(m8[2], m8[3])),
                    fmaxf(fmaxf(m8[4], m8[5]), fmaxf(m8[6], m8[7])));
    m = fmaxf(m, __shfl_xor(m, 16));
    m = fmaxf(m, __shfl_xor(m, 32));
    if (lane < 16) red[wave * 16 + n16] = m;
    __syncthreads();
    const float gm = fmaxf(fmaxf(red[n16], red[16 + n16]),
                           fmaxf(red[32 + n16], red[48 + n16]));
    float l0 = 0.f, l1 = 0.f, l2 = 0.f, l3 = 0.f;
    #pragma unroll
    for (int i = 0; i < 16; ++i) {
        const float p0 = __expf(s_reg[4*i+0] - gm);
        const float p1 = __expf(s_reg[4*i+1] - gm);
        const float p2 = __expf(s_reg[4*i+2] - gm);
        const float p3 = __expf(s_reg[4*i+3] - gm);
        s_reg[4*i+0] = p0; s_reg[4*i+1] = p1;
        s_reg[4*i+2] = p2; s_reg[4*i+3] = p3;
        l0 += p0; l1 += p1; l2 += p2; l3 += p3;
    }
    float lsum = (l0 + l1) + (l2 + l3);
    lsum += __shfl_xor(lsum, 16);
    lsum += __shfl_xor(lsum, 32);
    if (lane < 16) red[64 + wave * 16 + n16] = lsum;
    __syncthreads();
    const float inv = 1.f / (red[64 + n16] + red[80 + n16] +
                             red[96 + n16] + red[112 + n16]);
    #pragma unroll
    for (int i = 0; i < 64; ++i) s_reg[i] *= inv;

    // ---- attn: 16 x float4 stores; pack ALL of P (bf16) into LDS ----
    float* ab = attng + ((size_t)(b * TQ_ + q0 + n16)) * TK_ + kbase + quad * 4;
    #pragma unroll
    for (int kt = 0; kt < 16; ++kt)
        *(float4*)(ab + kt * 16) = make_float4(s_reg[kt*4+0], s_reg[kt*4+1],
                                               s_reg[kt*4+2], s_reg[kt*4+3]);
    #pragma unroll
    for (int kt = 0; kt < 16; ++kt) {
        uint2 u;
        u.x = cvt2(s_reg[kt*4+0], s_reg[kt*4+1]);
        u.y = cvt2(s_reg[kt*4+2], s_reg[kt*4+3]);
        *(uint2*)(pw + n16 * PSTR + kt * 16 + quad * 4) = u;
    }

    // ================= O^T = (V^T)(P^T), V^T frags direct =================
    f32x4 oacc[4];
    #pragma unroll
    for (int dg = 0; dg < 4; ++dg) oacc[dg] = (f32x4){0.f, 0.f, 0.f, 0.f};

    #pragma unroll
    for (int c = 0; c < 8; ++c) {
        Frag cur[4];
        #pragma unroll
        for (int dg = 0; dg < 4; ++dg) cur[dg] = vf[dg];
        if (c < 7) {
            #pragma unroll
            for (int dg = 0; dg < 4; ++dg)
                vf[dg].s = *(const short8*)(vrow + (size_t)(dg * 16) * TK_ + (c + 1) * 32);
        }
        Frag pf;
        pf.s = *(const short8*)(pw + n16 * PSTR + c * 32 + quad * 8);
        #pragma unroll
        for (int dg = 0; dg < 4; ++dg)
            oacc[dg] = __builtin_amdgcn_mfma_f32_16x16x32_bf16(cur[dg].s, pf.s, oacc[dg], 0, 0, 0);
    }

    // ---- cross-wave O reduction (stage O^T f32 in own P region) ----
    float* ow = (float*)pw;
    #pragma unroll
    for (int dg = 0; dg < 4; ++dg)
        *(f32x4*)&ow[n16 * 68 + dg * 16 + quad * 4] = oacc[dg];
    __syncthreads();
    {
        const int row = t >> 4, col = (t & 15) * 4;
        const float* base = (const float*)lds;
        float4 o = make_float4(0.f, 0.f, 0.f, 0.f);
        #pragma unroll
        for (int w = 0; w < 4; ++w) {
            const float4 x = *(const float4*)(base + w * (WVS / 2) + row * 68 + col);
            o.x += x.x; o.y += x.y; o.z += x.z; o.w += x.w;
        }
        *(float4*)(outg + ((size_t)(b * TQ_ + q0 + row)) * DD + col) = o;
    }
}

// ===================== FALLBACK (R3, verified) =====================
__global__ __launch_bounds__(256, 3) void attn_fallback_kernel(
    const float* __restrict__ qg, const float* __restrict__ kg,
    const float* __restrict__ vg, const int* __restrict__ maskg,
    float* __restrict__ outg, float* __restrict__ attng)
{
    __shared__ __align__(16) short lds[4 * WVS];
    __shared__ float red[128];

    const int t    = threadIdx.x;
    const int wave = t >> 6, lane = t & 63;
    const int quad = lane >> 4, n16 = lane & 15;
    const int b    = blockIdx.y;
    const int q0   = blockIdx.x * 16;
    const int kbase = wave * 256;

    short* pw = lds + wave * WVS;

    Frag aq[2];
    {
        const float* qp = qg + ((size_t)(b * TQ_ + q0 + n16)) * DD + quad * 8;
        #pragma unroll
        for (int f = 0; f < 2; ++f) {
            float4 x = *(const float4*)(qp + f * 32);
            float4 y = *(const float4*)(qp + f * 32 + 4);
            aq[f].u[0] = cvt2(0.125f * x.x, 0.125f * x.y);
            aq[f].u[1] = cvt2(0.125f * x.z, 0.125f * x.w);
            aq[f].u[2] = cvt2(0.125f * y.x, 0.125f * y.y);
            aq[f].u[3] = cvt2(0.125f * y.z, 0.125f * y.w);
        }
    }

    float s_reg[64];
    const float* kbp  = kg + (size_t)b * TK_ * DD;
    const int*   mrow = maskg + ((size_t)(b * TQ_ + q0 + n16)) * TK_ + kbase + quad * 4;
    #pragma unroll
    for (int h = 0; h < 2; ++h) {
        int4 mk[8];
        #pragma unroll
        for (int i = 0; i < 8; ++i)
            mk[i] = *(const int4*)(mrow + (h * 8 + i) * 16);
        #pragma unroll
        for (int i = 0; i < 8; ++i) {
            const int kt = h * 8 + i;
            const float* kp = kbp + (size_t)(kbase + kt * 16 + n16) * DD + quad * 8;
            Frag bk[2];
            #pragma unroll
            for (int f = 0; f < 2; ++f) {
                float4 x = *(const float4*)(kp + f * 32);
                float4 y = *(const float4*)(kp + f * 32 + 4);
                bk[f].u[0] = cvt2(x.x, x.y); bk[f].u[1] = cvt2(x.z, x.w);
                bk[f].u[2] = cvt2(y.x, y.y); bk[f].u[3] = cvt2(y.z, y.w);
            }
            f32x4 acc = {0.f, 0.f, 0.f, 0.f};
            acc = __builtin_amdgcn_mfma_f32_16x16x32_bf16(bk[0].s, aq[0].s, acc, 0, 0, 0);
            acc = __builtin_amdgcn_mfma_f32_16x16x32_bf16(bk[1].s, aq[1].s, acc, 0, 0, 0);
            s_reg[kt * 4 + 0] = acc[0] + (mk[i].x ? 0.f : -1e9f);
            s_reg[kt * 4 + 1] = acc[1] + (mk[i].y ? 0.f : -1e9f);
            s_reg[kt * 4 + 2] = acc[2] + (mk[i].z ? 0.f : -1e9f);
            s_reg[kt * 4 + 3] = acc[3] + (mk[i].w ? 0.f : -1e9f);
        }
    }

    const float* vb0 = vg + (size_t)b * TK_ * DD + (size_t)(kbase + quad * 8) * DD + n16;
    float vraw[32];
    #pragma unroll
    for (int u = 0; u < 32; ++u)
        vraw[u] = vb0[(size_t)(u & 7) * DD + (u >> 3) * 16];

    float m8[8];
    #pragma unroll
    for (int j = 0; j < 8; ++j) m8[j] = s_reg[j];
    #pragma unroll
    for (int i = 8; i < 64; i += 8)
        #pragma unroll
        for (int j = 0; j < 8; ++j) m8[j] = fmaxf(m8[j], s_reg[i + j]);
    float m = fmaxf(fmaxf(fmaxf(m8[0], m8[1]), fmaxf(m8[2], m8[3])),
                    fmaxf(fmaxf(m8[4], m8[5]), fmaxf(m8[6], m8[7])));
    m = fmaxf(m, __shfl_xor(m, 16));
    m = fmaxf(m, __shfl_xor(m, 32));
    if (lane < 16) red[wave * 16 + n16] = m;
    __syncthreads();
    const float gm = fmaxf(fmaxf(red[n16], red[16 + n16]),
                           fmaxf(red[32 + n16], red[48 + n16]));
    float l0 = 0.f, l1 = 0.f, l2 = 0.f, l3 = 0.f;
    #pragma unroll
    for (int i = 0; i < 16; ++i) {
        const float p0 = __expf(s_reg[4*i+0] - gm);
        const float p1 = __expf(s_reg[4*i+1] - gm);
        const float p2 = __expf(s_reg[4*i+2] - gm);
        const float p3 = __expf(s_reg[4*i+3] - gm);
        s_reg[4*i+0] = p0; s_reg[4*i+1] = p1;
        s_reg[4*i+2] = p2; s_reg[4*i+3] = p3;
        l0 += p0; l1 += p1; l2 += p2; l3 += p3;
    }
    float lsum = (l0 + l1) + (l2 + l3);
    lsum += __shfl_xor(lsum, 16);
    lsum += __shfl_xor(lsum, 32);
    if (lane < 16) red[64 + wave * 16 + n16] = lsum;
    __syncthreads();
    const float inv = 1.f / (red[64 + n16] + red[80 + n16] +
                             red[96 + n16] + red[112 + n16]);
    #pragma unroll
    for (int i = 0; i < 64; ++i) s_reg[i] *= inv;

    float* ab = attng + ((size_t)(b * TQ_ + q0 + n16)) * TK_ + kbase + quad * 4;
    #pragma unroll
    for (int kt = 0; kt < 16; ++kt)
        *(float4*)(ab + kt * 16) = make_float4(s_reg[kt*4+0], s_reg[kt*4+1],
                                               s_reg[kt*4+2], s_reg[kt*4+3]);
    #pragma unroll
    for (int kt = 0; kt < 16; ++kt) {
        uint2 u;
        u.x = cvt2(s_reg[kt*4+0], s_reg[kt*4+1]);
        u.y = cvt2(s_reg[kt*4+2], s_reg[kt*4+3]);
        *(uint2*)(pw + n16 * PSTR + kt * 16 + quad * 4) = u;
    }

    f32x4 oacc[4];
    #pragma unroll
    for (int dg = 0; dg < 4; ++dg) oacc[dg] = (f32x4){0.f, 0.f, 0.f, 0.f};

    #pragma unroll
    for (int c = 0; c < 8; ++c) {
        unsigned va16[16];
        #pragma unroll
        for (int dg = 0; dg < 4; ++dg)
            #pragma unroll
            for (int w = 0; w < 4; ++w)
                va16[dg * 4 + w] = cvt2(vraw[dg * 8 + 2 * w], vraw[dg * 8 + 2 * w + 1]);
        if (c < 7) {
            #pragma unroll
            for (int u = 0; u < 32; ++u)
                vraw[u] = vb0[(size_t)((c + 1) * 32 + (u & 7)) * DD + (u >> 3) * 16];
        }
        Frag pf;
        pf.s = *(const short8*)(pw + n16 * PSTR + c * 32 + quad * 8);
        #pragma unroll
        for (int dg = 0; dg < 4; ++dg) {
            Frag af;
            af.u[0] = va16[dg*4+0]; af.u[1] = va16[dg*4+1];
            af.u[2] = va16[dg*4+2]; af.u[3] = va16[dg*4+3];
            oacc[dg] = __builtin_amdgcn_mfma_f32_16x16x32_bf16(af.s, pf.s, oacc[dg], 0, 0, 0);
        }
    }

    float* ow = (float*)pw;
    #pragma unroll
    for (int dg = 0; dg < 4; ++dg)
        *(f32x4*)&ow[n16 * 68 + dg * 16 + quad * 4] = oacc[dg];
    __syncthreads();
    {
        const int row = t >> 4, col = (t & 15) * 4;
        const float* base = (const float*)lds;
        float4 o = make_float4(0.f, 0.f, 0.f, 0.f);
        #pragma unroll
        for (int w = 0; w < 4; ++w) {
            const float4 x = *(const float4*)(base + w * (WVS / 2) + row * 68 + col);
            o.x += x.x; o.y += x.y; o.z += x.z; o.w += x.w;
        }
        *(float4*)(outg + ((size_t)(b * TQ_ + q0 + row)) * DD + col) = o;
    }
}

extern "C" void kernel_launch(void* const* d_in, const int* in_sizes, int n_in,
                              void* d_out, int out_size, void* d_ws, size_t ws_size,
                              hipStream_t stream) {
    const float* q    = (const float*)d_in[0];
    const float* k    = (const float*)d_in[1];
    const float* v    = (const float*)d_in[2];
    const int*   mask = (const int*)d_in[3];

    float* out  = (float*)d_out;                   // [64][1024][64]
    float* attn = out + (size_t)B_ * TQ_ * DD;     // [64][1024][1024]

    if (ws_size >= (size_t)WS_NEED && d_ws != nullptr) {
        unsigned char* ws = (unsigned char*)d_ws;
        prep_kernel<<<dim3(12352), 256, 0, stream>>>(q, k, v, mask, ws);
        attn_bf16_kernel<<<dim3(TQ_ / 16, B_), 256, 0, stream>>>(ws, out, attn);
    } else {
        attn_fallback_kernel<<<dim3(TQ_ / 16, B_), 256, 0, stream>>>(q, k, v, mask, out, attn);
    }
}

// Round 5
// 615.749 us; speedup vs baseline: 1.0614x; 1.0306x over previous
//
#include <hip/hip_runtime.h>
#include <hip/hip_bf16.h>

// Two-pass bf16-MFMA attention with materialized attn.
// B=64, TQ=TK=1024, DK=DV=64.
//
// Pass 1 (prep): pure streaming —
//   - V -> V^T bf16 [b][d][k]   (1024 blocks: one per batch x 64-key tile)
//   - mask int32 -> 1 bit/entry (268 MB -> 8.4 MB for the main pass)
//   - Q -> bf16 (0.125 folded), K -> bf16
// Pass 2 (main): WG=256=4 waves, 16 queries/WG, wave w owns keys [w*256,+256).
//   S^T = mfma(K,Q); mask via bit-extract; V^T A-frags loaded directly
//   (1-chunk prefetch); P -> LDS in TWO 128-key halves (R2-verified pattern)
//   so per-wave LDS = 4352 B and total LDS = 17920 B -> 8 WG/CU (R4 was
//   34304 B -> 4 WG/CU, occupancy-capped at 41%).
// Falls back to the R3 single-pass kernel if ws_size < 32 MiB.

#define B_   64
#define TQ_  1024
#define TK_  1024
#define DD   64

typedef short short8 __attribute__((ext_vector_type(8)));
typedef float f32x4 __attribute__((ext_vector_type(4)));

#define PLW    68              // u32 per P row: 64 data (128 keys bf16) + 4 pad
#define PL_U32 (16 * PLW)      // 1088 u32 = 4352 B per wave (P half / O stage)

// workspace layout
#define QB_OFF  (0u)
#define KB_OFF  (8u << 20)
#define VT_OFF  (16u << 20)
#define MB_OFF  (24u << 20)
#define WS_NEED (32u << 20)    // 33554432 B

__device__ __forceinline__ unsigned cvt2(float a, float b) {
    __hip_bfloat162 h = __float22bfloat162_rn(make_float2(a, b));
    unsigned u; __builtin_memcpy(&u, &h, 4); return u;
}
__device__ __forceinline__ short cvt1(float a) {
    __hip_bfloat16 h = __float2bfloat16(a);
    short s; __builtin_memcpy(&s, &h, 2); return s;
}

union Frag { short8 s; unsigned u[4]; };

// ============================ PREP PASS ============================
// grid: [0,1024) V^T | [1024,9216) mask-pack | [9216,11264) Q | [11264,13312) K
__global__ __launch_bounds__(256) void prep_kernel(
    const float* __restrict__ qg, const float* __restrict__ kg,
    const float* __restrict__ vg, const int* __restrict__ maskg,
    unsigned char* __restrict__ ws)
{
    const int t = threadIdx.x;
    const int gid = blockIdx.x;
    if (gid < 1024) {
        // V^T for one (batch, 64-key tile): [64 k][64 d] f32 -> [64 d][64 k] bf16
        __shared__ short tl[64][72];
        const int b  = gid >> 4;
        const int k0 = (gid & 15) * 64;
        const float* vb = vg + (size_t)b * TK_ * DD;
        short* ob = (short*)(ws + VT_OFF) + (size_t)b * DD * TK_;
        #pragma unroll
        for (int i = 0; i < 4; ++i) {
            const int row = i * 16 + (t >> 4);
            const int d   = (t & 15) * 4;
            const float4 x = *(const float4*)(vb + (size_t)(k0 + row) * DD + d);
            tl[d + 0][row] = cvt1(x.x); tl[d + 1][row] = cvt1(x.y);
            tl[d + 2][row] = cvt1(x.z); tl[d + 3][row] = cvt1(x.w);
        }
        __syncthreads();
        #pragma unroll
        for (int p = 0; p < 2; ++p) {
            const int d = p * 32 + (t >> 3);
            const uint4 val = *(const uint4*)&tl[d][(t & 7) * 8];
            *(uint4*)(ob + (size_t)d * TK_ + k0 + (t & 7) * 8) = val;
        }
    } else if (gid < 1024 + 8192) {
        // one u32 of mask bits per thread: bit i = mask[widx*32 + i] & 1
        const int widx = (gid - 1024) * 256 + t;
        const int4* mp = (const int4*)(maskg + (size_t)widx * 32);
        unsigned bits = 0;
        #pragma unroll
        for (int i = 0; i < 8; ++i) {
            const int4 x = mp[i];
            bits |= (unsigned)(x.x & 1) << (4 * i)
                 |  (unsigned)(x.y & 1) << (4 * i + 1)
                 |  (unsigned)(x.z & 1) << (4 * i + 2)
                 |  (unsigned)(x.w & 1) << (4 * i + 3);
        }
        ((unsigned*)(ws + MB_OFF))[widx] = bits;
    } else if (gid < 1024 + 8192 + 2048) {
        const int i8 = (gid - 1024 - 8192) * 256 + t;   // 8 floats per thread
        const float* p = qg + (size_t)i8 * 8;
        const float4 x = *(const float4*)p, y = *(const float4*)(p + 4);
        uint4 o;
        o.x = cvt2(0.125f * x.x, 0.125f * x.y); o.y = cvt2(0.125f * x.z, 0.125f * x.w);
        o.z = cvt2(0.125f * y.x, 0.125f * y.y); o.w = cvt2(0.125f * y.z, 0.125f * y.w);
        ((uint4*)(ws + QB_OFF))[i8] = o;
    } else {
        const int i8 = (gid - 1024 - 8192 - 2048) * 256 + t;
        const float* p = kg + (size_t)i8 * 8;
        const float4 x = *(const float4*)p, y = *(const float4*)(p + 4);
        uint4 o;
        o.x = cvt2(x.x, x.y); o.y = cvt2(x.z, x.w);
        o.z = cvt2(y.x, y.y); o.w = cvt2(y.z, y.w);
        ((uint4*)(ws + KB_OFF))[i8] = o;
    }
}

// ============================ MAIN PASS ============================
__global__ __launch_bounds__(256, 4) void attn_bf16_kernel(
    const unsigned char* __restrict__ ws,
    float* __restrict__ outg, float* __restrict__ attng)
{
    __shared__ __align__(16) unsigned lds[4 * PL_U32];   // 17408 B
    __shared__ float red[128];                           // total 17920 B

    const int t    = threadIdx.x;
    const int wave = t >> 6, lane = t & 63;
    const int quad = lane >> 4, n16 = lane & 15;
    const int b    = blockIdx.y;
    const int q0   = blockIdx.x * 16;
    const int kbase = wave * 256;

    const short*    Qb = (const short*)(ws + QB_OFF);
    const short*    Kb = (const short*)(ws + KB_OFF);
    const short*    Vt = (const short*)(ws + VT_OFF);
    const unsigned* Mb = (const unsigned*)(ws + MB_OFF);

    unsigned* pl = lds + wave * PL_U32;

    // ---- mask words first (uncached stream, longest latency) ----
    const unsigned* mrow = Mb + ((size_t)(b * TQ_ + q0 + n16)) * 32 + wave * 8;
    const uint4 mw0 = *(const uint4*)(mrow);
    const uint4 mw1 = *(const uint4*)(mrow + 4);

    // ---- Q frags (bf16, pre-scaled) ----
    const short* qp = Qb + ((size_t)(b * TQ_ + q0 + n16)) * DD + quad * 8;
    Frag qf0, qf1;
    qf0.s = *(const short8*)(qp);
    qf1.s = *(const short8*)(qp + 32);

    // ---- V chunk-0 A-frags (direct from V^T, k contiguous) ----
    const short* vrow = Vt + (size_t)b * DD * TK_ + (size_t)n16 * TK_ + kbase + quad * 8;
    Frag vf[4];
    #pragma unroll
    for (int dg = 0; dg < 4; ++dg)
        vf[dg].s = *(const short8*)(vrow + (size_t)(dg * 16) * TK_);

    // ---- K frag pairs ----
    const short* kbp = Kb + (size_t)(b * TK_ + kbase) * DD;
    Frag kf[16][2];
    #pragma unroll
    for (int kt = 0; kt < 16; ++kt) {
        const short* kp = kbp + (size_t)(kt * 16 + n16) * DD + quad * 8;
        kf[kt][0].s = *(const short8*)(kp);
        kf[kt][1].s = *(const short8*)(kp + 32);
    }

    // ================= S^T = (K)(Q*0.125) + mask-bits =================
    float s_reg[64];  // s_reg[kt*4+r]: key kbase+kt*16+quad*4+r, query q0+n16
    const unsigned mwa[8] = {mw0.x, mw0.y, mw0.z, mw0.w, mw1.x, mw1.y, mw1.z, mw1.w};
    #pragma unroll
    for (int kt = 0; kt < 16; ++kt) {
        f32x4 acc = {0.f, 0.f, 0.f, 0.f};
        acc = __builtin_amdgcn_mfma_f32_16x16x32_bf16(kf[kt][0].s, qf0.s, acc, 0, 0, 0);
        acc = __builtin_amdgcn_mfma_f32_16x16x32_bf16(kf[kt][1].s, qf1.s, acc, 0, 0, 0);
        const unsigned m4 = (mwa[kt >> 1] >> (((kt & 1) << 4) | (quad << 2))) & 15u;
        s_reg[kt * 4 + 0] = acc[0] + ((m4 & 1u) ? 0.f : -1e9f);
        s_reg[kt * 4 + 1] = acc[1] + ((m4 & 2u) ? 0.f : -1e9f);
        s_reg[kt * 4 + 2] = acc[2] + ((m4 & 4u) ? 0.f : -1e9f);
        s_reg[kt * 4 + 3] = acc[3] + ((m4 & 8u) ? 0.f : -1e9f);
    }

    // ================= softmax =================
    float m8[8];
    #pragma unroll
    for (int j = 0; j < 8; ++j) m8[j] = s_reg[j];
    #pragma unroll
    for (int i = 8; i < 64; i += 8)
        #pragma unroll
        for (int j = 0; j < 8; ++j) m8[j] = fmaxf(m8[j], s_reg[i + j]);
    float m = fmaxf(fmaxf(fmaxf(m8[0], m8[1]), fmaxf(m8[2], m8[3])),
                    fmaxf(fmaxf(m8[4], m8[5]), fmaxf(m8[6], m8[7])));
    m = fmaxf(m, __shfl_xor(m, 16));
    m = fmaxf(m, __shfl_xor(m, 32));
    if (lane < 16) red[wave * 16 + n16] = m;
    __syncthreads();
    const float gm = fmaxf(fmaxf(red[n16], red[16 + n16]),
                           fmaxf(red[32 + n16], red[48 + n16]));
    float l0 = 0.f, l1 = 0.f, l2 = 0.f, l3 = 0.f;
    #pragma unroll
    for (int i = 0; i < 16; ++i) {
        const float p0 = __expf(s_reg[4*i+0] - gm);
        const float p1 = __expf(s_reg[4*i+1] - gm);
        const float p2 = __expf(s_reg[4*i+2] - gm);
        const float p3 = __expf(s_reg[4*i+3] - gm);
        s_reg[4*i+0] = p0; s_reg[4*i+1] = p1;
        s_reg[4*i+2] = p2; s_reg[4*i+3] = p3;
        l0 += p0; l1 += p1; l2 += p2; l3 += p3;
    }
    float lsum = (l0 + l1) + (l2 + l3);
    lsum += __shfl_xor(lsum, 16);
    lsum += __shfl_xor(lsum, 32);
    if (lane < 16) red[64 + wave * 16 + n16] = lsum;
    __syncthreads();
    const float inv = 1.f / (red[64 + n16] + red[80 + n16] +
                             red[96 + n16] + red[112 + n16]);
    #pragma unroll
    for (int i = 0; i < 64; ++i) s_reg[i] *= inv;

    // ---- attn: 16 x float4 stores; pack LOW 128 keys (bf16) into P-LDS ----
    float* ab = attng + ((size_t)(b * TQ_ + q0 + n16)) * TK_ + kbase + quad * 4;
    #pragma unroll
    for (int kt = 0; kt < 16; ++kt)
        *(float4*)(ab + kt * 16) = make_float4(s_reg[kt*4+0], s_reg[kt*4+1],
                                               s_reg[kt*4+2], s_reg[kt*4+3]);
    #pragma unroll
    for (int kt = 0; kt < 8; ++kt) {
        uint2 u;
        u.x = cvt2(s_reg[kt*4+0], s_reg[kt*4+1]);
        u.y = cvt2(s_reg[kt*4+2], s_reg[kt*4+3]);
        *(uint2*)&pl[n16 * PLW + kt * 8 + quad * 2] = u;
    }

    // ================= O^T = (V^T)(P^T), V^T frags direct =================
    f32x4 oacc[4];
    #pragma unroll
    for (int dg = 0; dg < 4; ++dg) oacc[dg] = (f32x4){0.f, 0.f, 0.f, 0.f};

    #pragma unroll
    for (int c = 0; c < 4; ++c) {          // key chunks 0..3 (low P half)
        Frag cur[4];
        #pragma unroll
        for (int dg = 0; dg < 4; ++dg) cur[dg] = vf[dg];
        #pragma unroll
        for (int dg = 0; dg < 4; ++dg)
            vf[dg].s = *(const short8*)(vrow + (size_t)(dg * 16) * TK_ + (c + 1) * 32);
        Frag pf;
        pf.s = *(const short8*)&pl[n16 * PLW + c * 16 + quad * 4];
        #pragma unroll
        for (int dg = 0; dg < 4; ++dg)
            oacc[dg] = __builtin_amdgcn_mfma_f32_16x16x32_bf16(cur[dg].s, pf.s, oacc[dg], 0, 0, 0);
    }

    // pack HIGH 128 keys (reads of low half already issued; same-wave DS in-order)
    #pragma unroll
    for (int kt = 8; kt < 16; ++kt) {
        uint2 u;
        u.x = cvt2(s_reg[kt*4+0], s_reg[kt*4+1]);
        u.y = cvt2(s_reg[kt*4+2], s_reg[kt*4+3]);
        *(uint2*)&pl[n16 * PLW + (kt - 8) * 8 + quad * 2] = u;
    }

    #pragma unroll
    for (int c = 0; c < 4; ++c) {          // key chunks 4..7 (high P half)
        Frag cur[4];
        #pragma unroll
        for (int dg = 0; dg < 4; ++dg) cur[dg] = vf[dg];
        if (c < 3) {
            #pragma unroll
            for (int dg = 0; dg < 4; ++dg)
                vf[dg].s = *(const short8*)(vrow + (size_t)(dg * 16) * TK_ + (c + 5) * 32);
        }
        Frag pf;
        pf.s = *(const short8*)&pl[n16 * PLW + c * 16 + quad * 4];
        #pragma unroll
        for (int dg = 0; dg < 4; ++dg)
            oacc[dg] = __builtin_amdgcn_mfma_f32_16x16x32_bf16(cur[dg].s, pf.s, oacc[dg], 0, 0, 0);
    }

    // ---- cross-wave O reduction (stage O^T f32 in own P region) ----
    // oacc[dg][r]: d = dg*16 + quad*4 + r, q = n16
    float* ow = (float*)pl;
    #pragma unroll
    for (int dg = 0; dg < 4; ++dg)
        *(f32x4*)&ow[n16 * PLW + dg * 16 + quad * 4] = oacc[dg];
    __syncthreads();
    {
        const int row = t >> 4, col = (t & 15) * 4;
        const float* base = (const float*)lds;
        float4 o = make_float4(0.f, 0.f, 0.f, 0.f);
        #pragma unroll
        for (int w = 0; w < 4; ++w) {
            const float4 x = *(const float4*)(base + w * PL_U32 + row * PLW + col);
            o.x += x.x; o.y += x.y; o.z += x.z; o.w += x.w;
        }
        *(float4*)(outg + ((size_t)(b * TQ_ + q0 + row)) * DD + col) = o;
    }
}

// ===================== FALLBACK (R3, verified) =====================
#define PSTR 264
#define FWVS (16 * PSTR)

__global__ __launch_bounds__(256, 3) void attn_fallback_kernel(
    const float* __restrict__ qg, const float* __restrict__ kg,
    const float* __restrict__ vg, const int* __restrict__ maskg,
    float* __restrict__ outg, float* __restrict__ attng)
{
    __shared__ __align__(16) short lds[4 * FWVS];
    __shared__ float red[128];

    const int t    = threadIdx.x;
    const int wave = t >> 6, lane = t & 63;
    const int quad = lane >> 4, n16 = lane & 15;
    const int b    = blockIdx.y;
    const int q0   = blockIdx.x * 16;
    const int kbase = wave * 256;

    short* pw = lds + wave * FWVS;

    Frag aq[2];
    {
        const float* qp = qg + ((size_t)(b * TQ_ + q0 + n16)) * DD + quad * 8;
        #pragma unroll
        for (int f = 0; f < 2; ++f) {
            float4 x = *(const float4*)(qp + f * 32);
            float4 y = *(const float4*)(qp + f * 32 + 4);
            aq[f].u[0] = cvt2(0.125f * x.x, 0.125f * x.y);
            aq[f].u[1] = cvt2(0.125f * x.z, 0.125f * x.w);
            aq[f].u[2] = cvt2(0.125f * y.x, 0.125f * y.y);
            aq[f].u[3] = cvt2(0.125f * y.z, 0.125f * y.w);
        }
    }

    float s_reg[64];
    const float* kbp  = kg + (size_t)b * TK_ * DD;
    const int*   mrow = maskg + ((size_t)(b * TQ_ + q0 + n16)) * TK_ + kbase + quad * 4;
    #pragma unroll
    for (int h = 0; h < 2; ++h) {
        int4 mk[8];
        #pragma unroll
        for (int i = 0; i < 8; ++i)
            mk[i] = *(const int4*)(mrow + (h * 8 + i) * 16);
        #pragma unroll
        for (int i = 0; i < 8; ++i) {
            const int kt = h * 8 + i;
            const float* kp = kbp + (size_t)(kbase + kt * 16 + n16) * DD + quad * 8;
            Frag bk[2];
            #pragma unroll
            for (int f = 0; f < 2; ++f) {
                float4 x = *(const float4*)(kp + f * 32);
                float4 y = *(const float4*)(kp + f * 32 + 4);
                bk[f].u[0] = cvt2(x.x, x.y); bk[f].u[1] = cvt2(x.z, x.w);
                bk[f].u[2] = cvt2(y.x, y.y); bk[f].u[3] = cvt2(y.z, y.w);
            }
            f32x4 acc = {0.f, 0.f, 0.f, 0.f};
            acc = __builtin_amdgcn_mfma_f32_16x16x32_bf16(bk[0].s, aq[0].s, acc, 0, 0, 0);
            acc = __builtin_amdgcn_mfma_f32_16x16x32_bf16(bk[1].s, aq[1].s, acc, 0, 0, 0);
            s_reg[kt * 4 + 0] = acc[0] + (mk[i].x ? 0.f : -1e9f);
            s_reg[kt * 4 + 1] = acc[1] + (mk[i].y ? 0.f : -1e9f);
            s_reg[kt * 4 + 2] = acc[2] + (mk[i].z ? 0.f : -1e9f);
            s_reg[kt * 4 + 3] = acc[3] + (mk[i].w ? 0.f : -1e9f);
        }
    }

    const float* vb0 = vg + (size_t)b * TK_ * DD + (size_t)(kbase + quad * 8) * DD + n16;
    float vraw[32];
    #pragma unroll
    for (int u = 0; u < 32; ++u)
        vraw[u] = vb0[(size_t)(u & 7) * DD + (u >> 3) * 16];

    float m8[8];
    #pragma unroll
    for (int j = 0; j < 8; ++j) m8[j] = s_reg[j];
    #pragma unroll
    for (int i = 8; i < 64; i += 8)
        #pragma unroll
        for (int j = 0; j < 8; ++j) m8[j] = fmaxf(m8[j], s_reg[i + j]);
    float m = fmaxf(fmaxf(fmaxf(m8[0], m8[1]), fmaxf(m8[2], m8[3])),
                    fmaxf(fmaxf(m8[4], m8[5]), fmaxf(m8[6], m8[7])));
    m = fmaxf(m, __shfl_xor(m, 16));
    m = fmaxf(m, __shfl_xor(m, 32));
    if (lane < 16) red[wave * 16 + n16] = m;
    __syncthreads();
    const float gm = fmaxf(fmaxf(red[n16], red[16 + n16]),
                           fmaxf(red[32 + n16], red[48 + n16]));
    float l0 = 0.f, l1 = 0.f, l2 = 0.f, l3 = 0.f;
    #pragma unroll
    for (int i = 0; i < 16; ++i) {
        const float p0 = __expf(s_reg[4*i+0] - gm);
        const float p1 = __expf(s_reg[4*i+1] - gm);
        const float p2 = __expf(s_reg[4*i+2] - gm);
        const float p3 = __expf(s_reg[4*i+3] - gm);
        s_reg[4*i+0] = p0; s_reg[4*i+1] = p1;
        s_reg[4*i+2] = p2; s_reg[4*i+3] = p3;
        l0 += p0; l1 += p1; l2 += p2; l3 += p3;
    }
    float lsum = (l0 + l1) + (l2 + l3);
    lsum += __shfl_xor(lsum, 16);
    lsum += __shfl_xor(lsum, 32);
    if (lane < 16) red[64 + wave * 16 + n16] = lsum;
    __syncthreads();
    const float inv = 1.f / (red[64 + n16] + red[80 + n16] +
                             red[96 + n16] + red[112 + n16]);
    #pragma unroll
    for (int i = 0; i < 64; ++i) s_reg[i] *= inv;

    float* ab = attng + ((size_t)(b * TQ_ + q0 + n16)) * TK_ + kbase + quad * 4;
    #pragma unroll
    for (int kt = 0; kt < 16; ++kt)
        *(float4*)(ab + kt * 16) = make_float4(s_reg[kt*4+0], s_reg[kt*4+1],
                                               s_reg[kt*4+2], s_reg[kt*4+3]);
    #pragma unroll
    for (int kt = 0; kt < 16; ++kt) {
        uint2 u;
        u.x = cvt2(s_reg[kt*4+0], s_reg[kt*4+1]);
        u.y = cvt2(s_reg[kt*4+2], s_reg[kt*4+3]);
        *(uint2*)(pw + n16 * PSTR + kt * 16 + quad * 4) = u;
    }

    f32x4 oacc[4];
    #pragma unroll
    for (int dg = 0; dg < 4; ++dg) oacc[dg] = (f32x4){0.f, 0.f, 0.f, 0.f};

    #pragma unroll
    for (int c = 0; c < 8; ++c) {
        unsigned va16[16];
        #pragma unroll
        for (int dg = 0; dg < 4; ++dg)
            #pragma unroll
            for (int w = 0; w < 4; ++w)
                va16[dg * 4 + w] = cvt2(vraw[dg * 8 + 2 * w], vraw[dg * 8 + 2 * w + 1]);
        if (c < 7) {
            #pragma unroll
            for (int u = 0; u < 32; ++u)
                vraw[u] = vb0[(size_t)((c + 1) * 32 + (u & 7)) * DD + (u >> 3) * 16];
        }
        Frag pf;
        pf.s = *(const short8*)(pw + n16 * PSTR + c * 32 + quad * 8);
        #pragma unroll
        for (int dg = 0; dg < 4; ++dg) {
            Frag af;
            af.u[0] = va16[dg*4+0]; af.u[1] = va16[dg*4+1];
            af.u[2] = va16[dg*4+2]; af.u[3] = va16[dg*4+3];
            oacc[dg] = __builtin_amdgcn_mfma_f32_16x16x32_bf16(af.s, pf.s, oacc[dg], 0, 0, 0);
        }
    }

    float* ow = (float*)pw;
    #pragma unroll
    for (int dg = 0; dg < 4; ++dg)
        *(f32x4*)&ow[n16 * 68 + dg * 16 + quad * 4] = oacc[dg];
    __syncthreads();
    {
        const int row = t >> 4, col = (t & 15) * 4;
        const float* base = (const float*)lds;
        float4 o = make_float4(0.f, 0.f, 0.f, 0.f);
        #pragma unroll
        for (int w = 0; w < 4; ++w) {
            const float4 x = *(const float4*)(base + w * (FWVS / 2) + row * 68 + col);
            o.x += x.x; o.y += x.y; o.z += x.z; o.w += x.w;
        }
        *(float4*)(outg + ((size_t)(b * TQ_ + q0 + row)) * DD + col) = o;
    }
}

extern "C" void kernel_launch(void* const* d_in, const int* in_sizes, int n_in,
                              void* d_out, int out_size, void* d_ws, size_t ws_size,
                              hipStream_t stream) {
    const float* q    = (const float*)d_in[0];
    const float* k    = (const float*)d_in[1];
    const float* v    = (const float*)d_in[2];
    const int*   mask = (const int*)d_in[3];

    float* out  = (float*)d_out;                   // [64][1024][64]
    float* attn = out + (size_t)B_ * TQ_ * DD;     // [64][1024][1024]

    if (ws_size >= (size_t)WS_NEED && d_ws != nullptr) {
        unsigned char* ws = (unsigned char*)d_ws;
        prep_kernel<<<dim3(13312), 256, 0, stream>>>(q, k, v, mask, ws);
        attn_bf16_kernel<<<dim3(TQ_ / 16, B_), 256, 0, stream>>>(ws, out, attn);
    } else {
        attn_fallback_kernel<<<dim3(TQ_ / 16, B_), 256, 0, stream>>>(q, k, v, mask, out, attn);
    }
}